// Round 1
// baseline (186.432 us; speedup 1.0000x reference)
//
#include <hip/hip_runtime.h>
#include <hip/hip_bf16.h>
#include <math.h>

#define NB 65536
#define DIN 1024
#define NQ 64
#define DOUT 1024

typedef __attribute__((ext_vector_type(8))) short bf16x8;
typedef __attribute__((ext_vector_type(4))) float f32x4;

__device__ __forceinline__ unsigned short f2bf(float f) {
    union { float f; unsigned u; } v; v.f = f;
    unsigned r = (v.u + 0x7fffu + ((v.u >> 16) & 1u)) >> 16;
    return (unsigned short)r;
}

// ---- kP: precompute bf16 weights + per-q constants --------------------------
__global__ __launch_bounds__(256) void kP(const float* __restrict__ W_in,
                                          const float* __restrict__ W_out,
                                          const float* __restrict__ qp,
                                          unsigned short* __restrict__ Wb,
                                          unsigned short* __restrict__ Wob,
                                          float* __restrict__ cp0,
                                          float* __restrict__ cq) {
    int i = blockIdx.x * 256 + threadIdx.x;
    if (i < NQ * DIN)  Wb[i]  = f2bf(W_in[i]);
    if (i < DOUT * NQ) Wob[i] = f2bf(W_out[i]);
    if (i < NQ) {
        cp0[i] = cosf(qp[i * 3 + 0]);
        cq[i]  = sinf(qp[i * 3 + 1]) * cosf(qp[i * 3 + 2]);
    }
}

// ---- kA: state = cos(pi/2 * tanh(x @ W_in.T + b_in)) * cp0 + cq -------------
// grid = NB/64 blocks of 256 threads (4 waves); wave w handles rows
// [blk*64 + w*16, +16), all 64 q columns. K-loop over DIN in steps of 32.
__global__ __launch_bounds__(256) void kA(const float* __restrict__ x,
                                          const unsigned short* __restrict__ Wb,
                                          const float* __restrict__ b_in,
                                          const float* __restrict__ cp0,
                                          const float* __restrict__ cq,
                                          unsigned short* __restrict__ state) {
    const int wave = threadIdx.x >> 6;
    const int lane = threadIdx.x & 63;
    const int r  = lane & 15;   // A row within 16-row tile / output col (q mod 16)
    const int kg = lane >> 4;   // k-group
    const int row0 = blockIdx.x * 64 + wave * 16;

    const float* xrow = x + (size_t)(row0 + r) * DIN + kg * 8;

    f32x4 acc[4] = {f32x4{0,0,0,0}, f32x4{0,0,0,0}, f32x4{0,0,0,0}, f32x4{0,0,0,0}};

    for (int k0 = 0; k0 < DIN; k0 += 32) {
        // A fragment: 8 contiguous f32 along K -> bf16
        float4 a0 = *(const float4*)(xrow + k0);
        float4 a1 = *(const float4*)(xrow + k0 + 4);
        bf16x8 a;
        a[0] = (short)f2bf(a0.x); a[1] = (short)f2bf(a0.y);
        a[2] = (short)f2bf(a0.z); a[3] = (short)f2bf(a0.w);
        a[4] = (short)f2bf(a1.x); a[5] = (short)f2bf(a1.y);
        a[6] = (short)f2bf(a1.z); a[7] = (short)f2bf(a1.w);
        #pragma unroll
        for (int n = 0; n < 4; n++) {
            // B fragment: W_in[q][k], q = n*16 + r, k = k0 + kg*8 + j (contiguous)
            bf16x8 b = *(const bf16x8*)(Wb + (size_t)(n * 16 + r) * DIN + k0 + kg * 8);
            acc[n] = __builtin_amdgcn_mfma_f32_16x16x32_bf16(a, b, acc[n], 0, 0, 0);
        }
    }

    // Epilogue. C/D layout: col = lane&15 (=r), row = (lane>>4)*4 + i
    #pragma unroll
    for (int n = 0; n < 4; n++) {
        int q = n * 16 + r;
        float bi = b_in[q], c0 = cp0[q], c1 = cq[q];
        #pragma unroll
        for (int i = 0; i < 4; i++) {
            int row = row0 + kg * 4 + i;
            float h = tanhf(acc[n][i] + bi);
            float s = cosf(h * 1.57079632679489662f) * c0 + c1;
            state[(size_t)row * NQ + q] = f2bf(s);
        }
    }
}

// ---- kB: out = state @ W_out.T + b_out --------------------------------------
// grid = NB/16 blocks of 256 threads (4 waves). Block handles 16 rows x 1024
// cols; wave w handles n-range [w*256, +256) = 16 n-tiles. K = 64 = 2 steps.
__global__ __launch_bounds__(256) void kB(const unsigned short* __restrict__ state,
                                          const unsigned short* __restrict__ Wob,
                                          const float* __restrict__ b_out,
                                          float* __restrict__ out) {
    const int wave = threadIdx.x >> 6;
    const int lane = threadIdx.x & 63;
    const int r  = lane & 15;
    const int kg = lane >> 4;
    const int row0 = blockIdx.x * 16;
    const int n0 = wave * 256;

    const unsigned short* srow = state + (size_t)(row0 + r) * NQ + kg * 8;
    bf16x8 a0 = *(const bf16x8*)(srow);
    bf16x8 a1 = *(const bf16x8*)(srow + 32);

    f32x4 acc[16];
    #pragma unroll
    for (int n = 0; n < 16; n++) acc[n] = f32x4{0, 0, 0, 0};

    #pragma unroll
    for (int n = 0; n < 16; n++) {
        int col = n0 + n * 16 + r;                 // W_out row / out col
        const unsigned short* wp = Wob + (size_t)col * NQ + kg * 8;
        bf16x8 b0 = *(const bf16x8*)(wp);
        bf16x8 b1 = *(const bf16x8*)(wp + 32);
        acc[n] = __builtin_amdgcn_mfma_f32_16x16x32_bf16(a0, b0, acc[n], 0, 0, 0);
        acc[n] = __builtin_amdgcn_mfma_f32_16x16x32_bf16(a1, b1, acc[n], 0, 0, 0);
    }

    #pragma unroll
    for (int n = 0; n < 16; n++) {
        int col = n0 + n * 16 + r;
        float bo = b_out[col];
        #pragma unroll
        for (int i = 0; i < 4; i++) {
            out[(size_t)(row0 + kg * 4 + i) * DOUT + col] = acc[n][i] + bo;
        }
    }
}

extern "C" void kernel_launch(void* const* d_in, const int* in_sizes, int n_in,
                              void* d_out, int out_size, void* d_ws, size_t ws_size,
                              hipStream_t stream) {
    const float* x    = (const float*)d_in[0];
    const float* W_in = (const float*)d_in[1];
    const float* b_in = (const float*)d_in[2];
    const float* qp   = (const float*)d_in[3];
    const float* W_out= (const float*)d_in[4];
    const float* b_out= (const float*)d_in[5];
    float* out = (float*)d_out;

    char* ws = (char*)d_ws;
    unsigned short* Wb    = (unsigned short*)(ws);            // 128 KB
    unsigned short* Wob   = (unsigned short*)(ws + 131072);   // 128 KB
    float*          cp0   = (float*)(ws + 262144);            // 256 B
    float*          cq    = (float*)(ws + 262400);            // 256 B
    unsigned short* state = (unsigned short*)(ws + 1048576);  // 8 MB

    kP<<<(NQ * DIN + 255) / 256, 256, 0, stream>>>(W_in, W_out, qp, Wb, Wob, cp0, cq);
    kA<<<NB / 64, 256, 0, stream>>>(x, Wb, b_in, cp0, cq, state);
    kB<<<NB / 16, 256, 0, stream>>>(state, Wob, b_out, out);
}